// Round 9
// baseline (258.011 us; speedup 1.0000x reference)
//
#include <hip/hip_runtime.h>

// DynamicConv2d: B=64, C=8, H=W=256, OUT_C=8, K=3, IN_FEAT=8
// out[b,oc,h,w] = sum_{ic,kh,kw} x[b,ic,h+kh-1,w+kw-1] *
//                 ( dot(dw[b,oc,:], Wg[ic*9+kh*3+kw,:]) + bg[ic*9+kh*3+kw] )
//
// Session log (conv-dispatch times):
//   R0: RPB=8 thread-per-col                                -> 90.6 us
//   R2-R5: launch_bounds(..,8) rounds: 32-VGPR cap -> spills masqueraded
//          as write amplification (WRITE up to 686 MB)      -> 101-300 us
//   R6: RPB=4 thread-per-col, no forcing, clean traffic     -> 88 us
//   R7: macro SW-pipeline: +21us issue > -10us stall        -> 98.7 us
//   R8: oc-paired pk FMA: 84.7 us (best). LESSON: v_pk_fma_f32 is NOT
//       double-rate on CDNA4 — plain v_fma_f32 (2cy/wave64) already is the
//       full 157.3 TF; pk halves instructions, not cycles.
//   R9 (this): R2's wave-per-row structure with both poisons removed
//       (plain stores, no launch-bounds forcing). Each wave owns 1 row,
//       each lane 4 cols: VMEM instrs/thread 144 -> 72 (aligned dwordx4
//       + 2 halo scalars per input row vs 3 scalar taps x 6 rows).
//   Rules learned: (1) __launch_bounds__ 2nd arg is a VGPR budget; over-ask
//   => scratch traffic (tripwire: WRITE_SIZE == 131072 KB exactly);
//   (2) plain stores only — nt-stores at <64B/lane get 4x write amp;
//   (3) shuffle halos & macro pipelines cost more VALU than they save;
//   (4) no packed-fp32 rate doubling on CDNA4.

#define HC   65536   // H*W
#define WW   256
#define RPB  4       // rows per block (4 waves x 1 row; fused fallback too)

typedef float floatx2 __attribute__((ext_vector_type(2)));
typedef float floatx4 __attribute__((ext_vector_type(4)));

// ---------------------------------------------------------------------------
// Kernel 1: materialize per-sample conv weights into d_ws with layout
//   kern[b][ic][kh][kw][oc]  (oc adjacent -> (oc,oc+1) float2 pairs)
// ---------------------------------------------------------------------------
__global__ __launch_bounds__(576) void gen_kernels(
    const float* __restrict__ dw,   // (B, 8, 8)
    const float* __restrict__ Wg,   // (72, 8)
    const float* __restrict__ bg,   // (72,)
    float* __restrict__ kern)       // (B, 576)
{
    const int b = blockIdx.x;
    const int j = threadIdx.x;
    if (j >= 576) return;
    const int ic   = j / 72;
    const int rem  = j % 72;
    const int kh   = rem / 24;
    const int rem2 = rem % 24;
    const int kw   = rem2 / 8;
    const int oc   = rem2 % 8;
    const int o    = ic * 9 + kh * 3 + kw;   // lin output index

    const float* d = dw + b * 64 + oc * 8;
    const float* g = Wg + o * 8;
    float v = bg[o];
#pragma unroll
    for (int i = 0; i < 8; ++i) v = fmaf(d[i], g[i], v);
    kern[b * 576 + j] = v;
}

// ---------------------------------------------------------------------------
// Kernel 2: the conv. Block = (sample b) x (4-row tile), 256 threads =
// 4 waves; each wave owns ONE output row, each lane 4 consecutive columns
// (64 x 4 = 256 = W). Per (ic, input-row): one ALIGNED dwordx4 + two
// L1-hit halo scalars = 3 VMEM instrs for 4 columns (vs 3 scalars per
// 1 column in the thread-per-col family). 72 VMEM instrs/thread total.
// acc[4 col][4 oc-pair] = 32 fp32 regs; NO launch-bounds min-waves
// (that poisoned R2-R5 with spills); plain dwordx4 stores (1 KB
// contiguous per wave per oc-row -> full-line writes).
// ---------------------------------------------------------------------------
__global__ __launch_bounds__(256) void dyn_conv_v4c(
    const float* __restrict__ x,     // (B, 8, 256, 256)
    const float* __restrict__ kern,  // (B, 576) in [ic][kh][kw][oc] layout
    float* __restrict__ out)         // (B, 8, 256, 256)
{
    const int b    = blockIdx.y;
    const int wv   = threadIdx.x >> 6;       // wave id 0..3
    const int lane = threadIdx.x & 63;
    const int h    = blockIdx.x * RPB + wv;  // this wave's output row
    const int w4   = lane << 2;              // first of 4 owned columns

    const float*   xb  = x + (size_t)b * 8 * HC;
    const floatx2* Kb2 = reinterpret_cast<const floatx2*>(kern + b * 576);
    float*         ob  = out + (size_t)b * 8 * HC;

    floatx2 acc[4][4];                       // [col][oc-pair] = 32 fp32
#pragma unroll
    for (int c = 0; c < 4; ++c)
#pragma unroll
        for (int p = 0; p < 4; ++p) acc[c][p] = (floatx2)(0.f);

#pragma unroll 1
    for (int ic = 0; ic < 8; ++ic) {
        // 36 wave-uniform float2 weights for this ic -> SGPR pairs
        floatx2 wk2[36];
        const floatx2* Kic2 = Kb2 + ic * 36;
#pragma unroll
        for (int t = 0; t < 36; ++t) wk2[t] = Kic2[t];

        const float* xch = xb + ic * HC;
#pragma unroll
        for (int kh = 0; kh < 3; ++kh) {
            const int row = h - 1 + kh;      // input row feeding weight row kh
            // xs = {xl, x0, x1, x2, x3, xr} — taps for 4 output columns
            float xs[6];
#pragma unroll
            for (int t = 0; t < 6; ++t) xs[t] = 0.f;
            if (row >= 0 && row < 256) {     // wave-uniform guard
                const float* xrow = xch + row * WW;
                const floatx4 v = *reinterpret_cast<const floatx4*>(xrow + w4);
                xs[1] = v.x; xs[2] = v.y; xs[3] = v.z; xs[4] = v.w;
                xs[0] = (w4 > 0)      ? xrow[w4 - 1] : 0.f;  // lane 0 edge
                xs[5] = (w4 + 4 < WW) ? xrow[w4 + 4] : 0.f;  // lane 63 edge
            }
            const floatx2* wr = &wk2[kh * 12];   // [kw][oc-pair]
#pragma unroll
            for (int c = 0; c < 4; ++c) {
                const floatx2 t0 = {xs[c],     xs[c]};
                const floatx2 t1 = {xs[c + 1], xs[c + 1]};
                const floatx2 t2 = {xs[c + 2], xs[c + 2]};
#pragma unroll
                for (int p = 0; p < 4; ++p) {
                    floatx2 a = acc[c][p];
                    a = __builtin_elementwise_fma(t0, wr[0 * 4 + p], a);
                    a = __builtin_elementwise_fma(t1, wr[1 * 4 + p], a);
                    a = __builtin_elementwise_fma(t2, wr[2 * 4 + p], a);
                    acc[c][p] = a;
                }
            }
        }
    }

    // Plain dwordx4 stores: per oc, the wave writes 1 KB contiguous.
    const size_t o0 = (size_t)h * WW + w4;
#pragma unroll
    for (int p = 0; p < 4; ++p) {
        floatx4 v0, v1;
        v0.x = acc[0][p].x; v0.y = acc[1][p].x; v0.z = acc[2][p].x; v0.w = acc[3][p].x;
        v1.x = acc[0][p].y; v1.y = acc[1][p].y; v1.z = acc[2][p].y; v1.w = acc[3][p].y;
        *reinterpret_cast<floatx4*>(ob + (2 * p)     * HC + o0) = v0;
        *reinterpret_cast<floatx4*>(ob + (2 * p + 1) * HC + o0) = v1;
    }
}

// ---------------------------------------------------------------------------
// Fallback: fused variant (weights computed into LDS) if ws is too small.
// ---------------------------------------------------------------------------
__global__ __launch_bounds__(256) void dyn_conv_fused(
    const float* __restrict__ x,
    const float* __restrict__ dw,
    const float* __restrict__ Wg,
    const float* __restrict__ bg,
    float* __restrict__ out)
{
    __shared__ float kl[576];
    const int b  = blockIdx.y;
    const int h0 = blockIdx.x * RPB;
    const int w  = threadIdx.x;

    for (int j = threadIdx.x; j < 576; j += 256) {
        const int ic   = j / 72;
        const int rem  = j % 72;
        const int kh   = rem / 24;
        const int rem2 = rem % 24;
        const int kw   = rem2 / 8;
        const int oc   = rem2 % 8;
        const int o    = ic * 9 + kh * 3 + kw;
        const float* d = dw + b * 64 + oc * 8;
        const float* g = Wg + o * 8;
        float v = bg[o];
#pragma unroll
        for (int i = 0; i < 8; ++i) v = fmaf(d[i], g[i], v);
        kl[j] = v;
    }
    __syncthreads();

    const float* xb = x + (size_t)b * 8 * HC;
    float*       ob = out + (size_t)b * 8 * HC;

    float acc[RPB][8];
#pragma unroll
    for (int r = 0; r < RPB; ++r)
#pragma unroll
        for (int oc = 0; oc < 8; ++oc) acc[r][oc] = 0.f;

#pragma unroll 1
    for (int ic = 0; ic < 8; ++ic) {
        const float* xch = xb + ic * HC;
#pragma unroll
        for (int ri = 0; ri < RPB + 2; ++ri) {
            const int row = h0 - 1 + ri;
            float xm = 0.f, xc = 0.f, xp = 0.f;
            if (row >= 0 && row < 256) {
                const float* xr = xch + row * WW;
                xc = xr[w];
                xm = (w > 0)   ? xr[w - 1] : 0.f;
                xp = (w < 255) ? xr[w + 1] : 0.f;
            }
#pragma unroll
            for (int kh = 0; kh < 3; ++kh) {
                const int ro = ri - kh;
                if (ro < 0 || ro >= RPB) continue;
                const float* wr = &kl[0] + ic * 72 + kh * 24;
#pragma unroll
                for (int oc = 0; oc < 8; ++oc) {
                    float a = acc[ro][oc];
                    a = fmaf(xm, wr[0 * 8 + oc], a);
                    a = fmaf(xc, wr[1 * 8 + oc], a);
                    a = fmaf(xp, wr[2 * 8 + oc], a);
                    acc[ro][oc] = a;
                }
            }
        }
    }

    const int hw0 = h0 * WW + w;
#pragma unroll
    for (int oc = 0; oc < 8; ++oc) {
        float* orow = ob + oc * HC + hw0;
#pragma unroll
        for (int r = 0; r < RPB; ++r) orow[r * WW] = acc[r][oc];
    }
}

extern "C" void kernel_launch(void* const* d_in, const int* in_sizes, int n_in,
                              void* d_out, int out_size, void* d_ws, size_t ws_size,
                              hipStream_t stream) {
    const float* x  = (const float*)d_in[0];  // (64,8,256,256)
    const float* dw = (const float*)d_in[1];  // (64,8,8)
    const float* Wg = (const float*)d_in[2];  // (72,8)
    const float* bg = (const float*)d_in[3];  // (72,)
    float* out = (float*)d_out;

    const dim3 grid(256 / RPB, 64);   // 64 row-tiles x 64 samples
    const dim3 block(256);

    if (ws_size >= (size_t)(64 * 576 * sizeof(float))) {
        float* kern = (float*)d_ws;
        gen_kernels<<<dim3(64), dim3(576), 0, stream>>>(dw, Wg, bg, kern);
        dyn_conv_v4c<<<grid, block, 0, stream>>>(x, kern, out);
    } else {
        dyn_conv_fused<<<grid, block, 0, stream>>>(x, dw, Wg, bg, out);
    }
}

// Round 10
// 241.840 us; speedup vs baseline: 1.0669x; 1.0669x over previous
//
#include <hip/hip_runtime.h>

// DynamicConv2d: B=64, C=8, H=W=256, OUT_C=8, K=3, IN_FEAT=8
// out[b,oc,h,w] = sum_{ic,kh,kw} x[b,ic,h+kh-1,w+kw-1] *
//                 ( dot(dw[b,oc,:], Wg[ic*9+kh*3+kw,:]) + bg[ic*9+kh*3+kw] )
//
// Session log (conv-dispatch times):
//   R0: RPB=8 thread-per-col                                 -> 90.6 us
//   R2-R5: launch_bounds(..,8): 32-VGPR cap -> spills        -> 101-300 us
//   R6: RPB=4 thread-per-col, clean                          -> 88 us
//   R7: macro SW-pipeline: issue bloat > stall saved         -> 98.7 us
//   R8: oc-paired pk FMA (best)                              -> 84.7 us
//   R9: wave-per-row dwordx4+halo: stall UP (fewer streams)  -> 97.2 us
//   Model: all variants = ~42 us VALU issue + ~45 us latency stall;
//   per-ic synchronous {load 4.6KB -> wait -> compute} caps achieved BW
//   at ~2.7 TB/s (Little's law).
//   R10 (this): bulk async prefetch — stage ALL 48 KB (8ic x 6 rows) into
//   LDS via global_load_lds(width16) at block start (12-16 instrs/wave all
//   outstanding), ONE barrier, then R8's exact pk-FMA core reading taps
//   from LDS. 3 blocks/CU pipeline: one stages while two compute.
//   Rules learned: (1) __launch_bounds__ 2nd arg is a VGPR budget; over-ask
//   => scratch traffic (tripwire: WRITE_SIZE == 131072 KB exactly);
//   (2) plain stores only — nt-stores <64B/lane get 4x write amp;
//   (3) shuffles/macro-pipelines/fewer-fatter-loads all lost to the simple
//   scalar thread-per-col pattern; (4) no packed-fp32 rate doubling.

#define HC   65536   // H*W
#define WW   256
#define RPB  4       // output rows per block; staged input rows = RPB+2 = 6

typedef float floatx2 __attribute__((ext_vector_type(2)));

// async 16B-per-lane global->LDS (wave-uniform LDS base + lane*16 dest)
__device__ __forceinline__ void gload_lds16(const float* g, float* l) {
    __builtin_amdgcn_global_load_lds(
        (const __attribute__((address_space(1))) void*)g,
        (__attribute__((address_space(3))) void*)l, 16, 0, 0);
}

// ---------------------------------------------------------------------------
// Kernel 1: materialize per-sample conv weights into d_ws with layout
//   kern[b][ic][kh][kw][oc]  (oc adjacent -> (oc,oc+1) float2 pairs)
// ---------------------------------------------------------------------------
__global__ __launch_bounds__(576) void gen_kernels(
    const float* __restrict__ dw,   // (B, 8, 8)
    const float* __restrict__ Wg,   // (72, 8)
    const float* __restrict__ bg,   // (72,)
    float* __restrict__ kern)       // (B, 576)
{
    const int b = blockIdx.x;
    const int j = threadIdx.x;
    if (j >= 576) return;
    const int ic   = j / 72;
    const int rem  = j % 72;
    const int kh   = rem / 24;
    const int rem2 = rem % 24;
    const int kw   = rem2 / 8;
    const int oc   = rem2 % 8;
    const int o    = ic * 9 + kh * 3 + kw;   // lin output index

    const float* d = dw + b * 64 + oc * 8;
    const float* g = Wg + o * 8;
    float v = bg[o];
#pragma unroll
    for (int i = 0; i < 8; ++i) v = fmaf(d[i], g[i], v);
    kern[b * 576 + j] = v;
}

// ---------------------------------------------------------------------------
// Kernel 2: the conv. One block = one sample b x one 4-row tile, 256
// threads = one thread per W column. Phase 1: async-stage the block's
// whole input working set (8 ic x 6 rows = 48 KB) to LDS — each wave
// issues <=16 global_load_lds (1 KB each), ALL outstanding at once.
// Phase 2 (after one barrier): R8's pk-FMA core with taps read from LDS
// (consecutive-lane stride-1 -> conflict-free). Stores identical to R8.
// ---------------------------------------------------------------------------
__global__ __launch_bounds__(256) void dyn_conv_lds(
    const float* __restrict__ x,     // (B, 8, 256, 256)
    const float* __restrict__ kern,  // (B, 576) in [ic][kh][kw][oc] layout
    float* __restrict__ out)         // (B, 8, 256, 256)
{
    __shared__ float sx[8][6][256];          // 48 KB

    const int b    = blockIdx.y;
    const int h0   = blockIdx.x * RPB;
    const int w    = threadIdx.x;            // column 0..255
    const int wv   = threadIdx.x >> 6;       // wave 0..3
    const int lane = threadIdx.x & 63;

    const float*   xb  = x + (size_t)b * 8 * HC;
    const floatx2* Kb2 = reinterpret_cast<const floatx2*>(kern + b * 576);
    float*         ob  = out + (size_t)b * 8 * HC;

    // Zero-fill the (at most one) out-of-image halo row — block-uniform.
    if (h0 == 0) {
#pragma unroll
        for (int ic = 0; ic < 8; ++ic) sx[ic][0][w] = 0.f;
    }
    if (h0 == 256 - RPB) {
#pragma unroll
        for (int ic = 0; ic < 8; ++ic) sx[ic][5][w] = 0.f;
    }

    // Bulk async stage: wave wv covers rows r = wv and wv+4 (r<6) of each ic.
    // Per instr: 64 lanes x 16 B = one full 1 KB image row into LDS.
#pragma unroll
    for (int ic = 0; ic < 8; ++ic) {
        const float* xch = xb + ic * HC;
#pragma unroll
        for (int r0 = 0; r0 < 2; ++r0) {
            const int r = wv + r0 * 4;               // wave-uniform
            if (r < 6) {
                const int row = h0 - 1 + r;
                if (row >= 0 && row < 256) {
                    gload_lds16(xch + row * WW + (lane << 2), &sx[ic][r][0]);
                }
            }
        }
    }
    __syncthreads();   // drains vmcnt; staged data + zero rows now valid

    floatx2 acc[RPB][4];                     // [row][oc-pair] = 32 fp32
#pragma unroll
    for (int r = 0; r < RPB; ++r)
#pragma unroll
        for (int p = 0; p < 4; ++p) acc[r][p] = (floatx2)(0.f);

#pragma unroll 1
    for (int ic = 0; ic < 8; ++ic) {
        // 36 wave-uniform float2 weights for this ic -> SGPR pairs
        floatx2 wk2[36];
        const floatx2* Kic2 = Kb2 + ic * 36;
#pragma unroll
        for (int t = 0; t < 36; ++t) wk2[t] = Kic2[t];

#pragma unroll
        for (int ri = 0; ri < RPB + 2; ++ri) {
            const float xc = sx[ic][ri][w];
            const float xm = (w > 0)   ? sx[ic][ri][w - 1] : 0.f;
            const float xp = (w < 255) ? sx[ic][ri][w + 1] : 0.f;
            const floatx2 vm = {xm, xm};
            const floatx2 vc = {xc, xc};
            const floatx2 vp = {xp, xp};
#pragma unroll
            for (int kh = 0; kh < 3; ++kh) {
                const int ro = ri - kh;
                if (ro < 0 || ro >= RPB) continue;  // compile-time pruned
                const floatx2* wr = &wk2[kh * 12];  // [kw][oc-pair]
#pragma unroll
                for (int p = 0; p < 4; ++p) {
                    floatx2 a = acc[ro][p];
                    a = __builtin_elementwise_fma(vm, wr[0 * 4 + p], a);
                    a = __builtin_elementwise_fma(vc, wr[1 * 4 + p], a);
                    a = __builtin_elementwise_fma(vp, wr[2 * 4 + p], a);
                    acc[ro][p] = a;
                }
            }
        }
    }

    // Stores: identical pattern to R8 (proven WRITE = 131072 KB exact).
    const int hw0 = h0 * WW + w;
#pragma unroll
    for (int p = 0; p < 4; ++p) {
        float* orow0 = ob + (2 * p)     * HC + hw0;
        float* orow1 = ob + (2 * p + 1) * HC + hw0;
#pragma unroll
        for (int r = 0; r < RPB; ++r) {
            orow0[r * WW] = acc[r][p].x;
            orow1[r * WW] = acc[r][p].y;
        }
    }
}

// ---------------------------------------------------------------------------
// Fallback: fused variant (weights computed into LDS) if ws is too small.
// ---------------------------------------------------------------------------
__global__ __launch_bounds__(256) void dyn_conv_fused(
    const float* __restrict__ x,
    const float* __restrict__ dw,
    const float* __restrict__ Wg,
    const float* __restrict__ bg,
    float* __restrict__ out)
{
    __shared__ float kl[576];
    const int b  = blockIdx.y;
    const int h0 = blockIdx.x * RPB;
    const int w  = threadIdx.x;

    for (int j = threadIdx.x; j < 576; j += 256) {
        const int ic   = j / 72;
        const int rem  = j % 72;
        const int kh   = rem / 24;
        const int rem2 = rem % 24;
        const int kw   = rem2 / 8;
        const int oc   = rem2 % 8;
        const int o    = ic * 9 + kh * 3 + kw;
        const float* d = dw + b * 64 + oc * 8;
        const float* g = Wg + o * 8;
        float v = bg[o];
#pragma unroll
        for (int i = 0; i < 8; ++i) v = fmaf(d[i], g[i], v);
        kl[j] = v;
    }
    __syncthreads();

    const float* xb = x + (size_t)b * 8 * HC;
    float*       ob = out + (size_t)b * 8 * HC;

    float acc[RPB][8];
#pragma unroll
    for (int r = 0; r < RPB; ++r)
#pragma unroll
        for (int oc = 0; oc < 8; ++oc) acc[r][oc] = 0.f;

#pragma unroll 1
    for (int ic = 0; ic < 8; ++ic) {
        const float* xch = xb + ic * HC;
#pragma unroll
        for (int ri = 0; ri < RPB + 2; ++ri) {
            const int row = h0 - 1 + ri;
            float xm = 0.f, xc = 0.f, xp = 0.f;
            if (row >= 0 && row < 256) {
                const float* xr = xch + row * WW;
                xc = xr[w];
                xm = (w > 0)   ? xr[w - 1] : 0.f;
                xp = (w < 255) ? xr[w + 1] : 0.f;
            }
#pragma unroll
            for (int kh = 0; kh < 3; ++kh) {
                const int ro = ri - kh;
                if (ro < 0 || ro >= RPB) continue;
                const float* wr = &kl[0] + ic * 72 + kh * 24;
#pragma unroll
                for (int oc = 0; oc < 8; ++oc) {
                    float a = acc[ro][oc];
                    a = fmaf(xm, wr[0 * 8 + oc], a);
                    a = fmaf(xc, wr[1 * 8 + oc], a);
                    a = fmaf(xp, wr[2 * 8 + oc], a);
                    acc[ro][oc] = a;
                }
            }
        }
    }

    const int hw0 = h0 * WW + w;
#pragma unroll
    for (int oc = 0; oc < 8; ++oc) {
        float* orow = ob + oc * HC + hw0;
#pragma unroll
        for (int r = 0; r < RPB; ++r) orow[r * WW] = acc[r][oc];
    }
}

extern "C" void kernel_launch(void* const* d_in, const int* in_sizes, int n_in,
                              void* d_out, int out_size, void* d_ws, size_t ws_size,
                              hipStream_t stream) {
    const float* x  = (const float*)d_in[0];  // (64,8,256,256)
    const float* dw = (const float*)d_in[1];  // (64,8,8)
    const float* Wg = (const float*)d_in[2];  // (72,8)
    const float* bg = (const float*)d_in[3];  // (72,)
    float* out = (float*)d_out;

    const dim3 grid(256 / RPB, 64);   // 64 row-tiles x 64 samples
    const dim3 block(256);

    if (ws_size >= (size_t)(64 * 576 * sizeof(float))) {
        float* kern = (float*)d_ws;
        gen_kernels<<<dim3(64), dim3(576), 0, stream>>>(dw, Wg, bg, kern);
        dyn_conv_lds<<<grid, block, 0, stream>>>(x, kern, out);
    } else {
        dyn_conv_fused<<<grid, block, 0, stream>>>(x, dw, Wg, bg, out);
    }
}